// Round 10
// baseline (793.003 us; speedup 1.0000x reference)
//
#include <hip/hip_runtime.h>
#include <stdint.h>

#define NN 60000
#define NE 1920000
#define NB_NODE 235   // ceil(60000/256)
#define NB_QUAD 938   // ceil(60000/64) for 4-thread-per-node kernels
#define EB4 1875      // NE/(256*4) exactly: blocks per bucket pass
#define CAP 128       // bucket capacity per node (P(deg>=128) ~ 0, dataset fixed)
#define RN 7500       // dst-range width per pass (60000/8): 7500*128*2B = 1.9MB < 4MB L2

typedef float f32x4 __attribute__((ext_vector_type(4)));
typedef short s16x8 __attribute__((ext_vector_type(8)));

__device__ __forceinline__ uint16_t f2bf(float f) {
  union { float f; uint32_t u; } v; v.f = f;
  uint32_t r = v.u + 0x7FFFu + ((v.u >> 16) & 1u);
  return (uint16_t)(r >> 16);
}
__device__ __forceinline__ uint32_t pack2(float a, float b) {
  return (uint32_t)f2bf(a) | ((uint32_t)f2bf(b) << 16);
}
__device__ __forceinline__ void unpack2(uint32_t w, float& lo, float& hi) {
  union { uint32_t u; float f; } a, b;
  a.u = w << 16; b.u = w & 0xffff0000u;
  lo = a.f; hi = b.f;
}
__device__ __forceinline__ float elu1(float x) { return x > 0.f ? x : (__expf(x) - 1.f); }

__device__ __forceinline__ void load8(const float* __restrict__ p, float* v) {
  const float4* q = (const float4*)p;
  float4 a = q[0], b = q[1];
  v[0]=a.x; v[1]=a.y; v[2]=a.z; v[3]=a.w; v[4]=b.x; v[5]=b.y; v[6]=b.z; v[7]=b.w;
}
__device__ __forceinline__ void load16(const float* __restrict__ p, float* v) {
  load8(p, v); load8(p + 8, v + 8);
}
__device__ __forceinline__ void store16(float* __restrict__ p, const float* v) {
  float4* q = (float4*)p;
  q[0] = make_float4(v[0],v[1],v[2],v[3]);
  q[1] = make_float4(v[4],v[5],v[6],v[7]);
  q[2] = make_float4(v[8],v[9],v[10],v[11]);
  q[3] = make_float4(v[12],v[13],v[14],v[15]);
}

// ---------------- fused prep: bucket (15000 blk) | transposes (2700) | proj12 (235) ----
__global__ void prep_k(const int* __restrict__ src, const int* __restrict__ dst,
                       int* __restrict__ deg, uint16_t* __restrict__ sb,
                       const float* __restrict__ W1, const float* __restrict__ W2,
                       const float* __restrict__ W3,
                       uint16_t* __restrict__ W1T, uint16_t* __restrict__ W2T,
                       uint16_t* __restrict__ W3T,
                       const float* __restrict__ x,
                       const float* __restrict__ Ws1, const float* __restrict__ Wd1,
                       const float* __restrict__ Ws2, const float* __restrict__ Wd2,
                       uint32_t* __restrict__ fs12b, float* __restrict__ fd12) {
  int b = blockIdx.x;
  int tid = threadIdx.x;

  if (b < 8 * EB4) {
    // --- bucket: pass p handles dst in [p*RN,(p+1)*RN); 4 edges/thread via int4 ---
    int p = b / EB4;
    int idx = (b - p * EB4) * 256 + tid;
    int4 d4 = ((const int4*)dst)[idx];
    int4 s4 = ((const int4*)src)[idx];
    int lo = p * RN;
    int dd[4] = {d4.x, d4.y, d4.z, d4.w};
    int ss[4] = {s4.x, s4.y, s4.z, s4.w};
    #pragma unroll
    for (int j = 0; j < 4; ++j) {
      int d = dd[j];
      if (d >= lo && d < lo + RN) {
        int pos = atomicAdd(&deg[d], 1);
        if (pos < CAP) sb[(size_t)d * CAP + pos] = (uint16_t)ss[j];
      }
    }
    return;
  }
  b -= 8 * EB4;

  if (b < 2700) {
    // --- weight transposes to bf16 ---
    __shared__ float t[32][33];
    const float* in; uint16_t* outT; int R, C, ldout, rb, cb;
    if (b < 100)       { in = W1; outT = W1T; R = 40;   C = 1600; ldout = 64;
                         rb = (b % 2) * 32;        cb = (b / 2) * 32; }
    else if (b < 2600) { int u = b - 100; in = W2; outT = W2T; R = 1600; C = 1600; ldout = 1600;
                         rb = (u % 50) * 32;       cb = (u / 50) * 32; }
    else               { int u = b - 2600; in = W3; outT = W3T; R = 1600; C = 40;  ldout = 1600;
                         rb = (u % 50) * 32;       cb = (u / 50) * 32; }
    int tx = tid & 31, ty = tid >> 5;
    #pragma unroll
    for (int y = ty; y < 32; y += 8) {
      int r = rb + y, c = cb + tx;
      t[y][tx] = (r < R && c < C) ? in[(size_t)r * C + c] : 0.f;
    }
    __syncthreads();
    #pragma unroll
    for (int y = ty; y < 32; y += 8) {
      int c = cb + y, r = rb + tx;
      if (c < C && r < R) outT[(size_t)c * ldout + r] = f2bf(t[tx][y]);
    }
    return;
  }
  b -= 2700;

  // --- proj12: fs12b bf16 [fs1|fs2], fd12 fp32 [fd1|fd2] ---
  __shared__ float w[4][128];
  if (tid < 128) {
    w[0][tid] = Ws1[tid]; w[1][tid] = Wd1[tid];
    w[2][tid] = Ws2[tid]; w[3][tid] = Wd2[tid];
  }
  __syncthreads();
  int n = b * 256 + tid;
  if (n >= NN) return;
  float xi[8]; load8(x + (size_t)n * 8, xi);
  float o[16];
  uint32_t fsw[16];
  #pragma unroll
  for (int m = 0; m < 4; ++m) {
    #pragma unroll
    for (int j = 0; j < 16; ++j) {
      float a = 0.f;
      #pragma unroll
      for (int i = 0; i < 8; ++i) a += xi[i] * w[m][i*16 + j];
      o[j] = a;
    }
    if (m & 1) {
      store16(fd12 + (size_t)n * 32 + (m >> 1) * 16, o);
    } else {
      #pragma unroll
      for (int j = 0; j < 8; ++j) fsw[(m >> 1) * 8 + j] = pack2(o[2*j], o[2*j+1]);
    }
  }
  uint4* fp = (uint4*)(fs12b + (size_t)n * 16);
  fp[0] = make_uint4(fsw[0], fsw[1], fsw[2], fsw[3]);
  fp[1] = make_uint4(fsw[4], fsw[5], fsw[6], fsw[7]);
  fp[2] = make_uint4(fsw[8], fsw[9], fsw[10], fsw[11]);
  fp[3] = make_uint4(fsw[12], fsw[13], fsw[14], fsw[15]);
}

// ---------------- gathers (4 threads per node, quad-shfl-combined; R7-proven) ------

__global__ __launch_bounds__(256) void gather12_p3(
    const int* __restrict__ deg, const uint16_t* __restrict__ sb,
    const uint32_t* __restrict__ fs12b, const float* __restrict__ fd12,
    const float* __restrict__ at1, const float* __restrict__ at2,
    const float* __restrict__ x,
    const float* __restrict__ re1, const float* __restrict__ bi1,
    const float* __restrict__ re2, const float* __restrict__ bi2,
    const float* __restrict__ Ws3, const float* __restrict__ Wd3,
    uint32_t* __restrict__ hinb32, float* __restrict__ hdef1,
    uint32_t* __restrict__ fs3b, float* __restrict__ fd3) {
  __shared__ float r1[128], r2[128], ws3[256], wd3[256];
  __shared__ float atA[16], atB[16], b1s[16], b2s[16];
  int tid = threadIdx.x;
  if (tid < 128) { r1[tid] = re1[tid]; r2[tid] = re2[tid]; }
  ws3[tid] = Ws3[tid]; wd3[tid] = Wd3[tid];
  if (tid < 16) { atA[tid] = at1[tid]; atB[tid] = at2[tid];
                  b1s[tid] = bi1[tid]; b2s[tid] = bi2[tid]; }
  __syncthreads();
  int n = blockIdx.x * 64 + (tid >> 2);
  int q = tid & 3;
  bool alive = (n < NN);
  float fd[32];
  float acc[32];
  #pragma unroll
  for (int i = 0; i < 32; ++i) acc[i] = 0.f;
  float z[4] = {0.f, 0.f, 0.f, 0.f};
  int d = 0;
  const uint16_t* sp = sb + (size_t)n * CAP;
  if (alive) {
    load16(fd12 + (size_t)n * 32, fd);
    load16(fd12 + (size_t)n * 32 + 16, fd + 16);
    d = deg[n]; if (d > CAP) d = CAP;
  }
  for (int i = q; i < d; i += 4) {
    int s = sp[i];
    const uint4* fp = (const uint4*)(fs12b + (size_t)s * 16);
    uint4 u0 = fp[0], u1 = fp[1], u2 = fp[2], u3 = fp[3];
    uint32_t wv[16] = {u0.x,u0.y,u0.z,u0.w, u1.x,u1.y,u1.z,u1.w,
                       u2.x,u2.y,u2.z,u2.w, u3.x,u3.y,u3.z,u3.w};
    float fs[32];
    #pragma unroll
    for (int k = 0; k < 16; ++k) unpack2(wv[k], fs[2*k], fs[2*k+1]);
    #pragma unroll
    for (int L = 0; L < 2; ++L) {
      #pragma unroll
      for (int h = 0; h < 2; ++h) {
        float sc = 0.f;
        #pragma unroll
        for (int d0 = 0; d0 < 8; ++d0) {
          int ix = L*16 + h*8 + d0;
          float e = fs[ix] + fd[ix];
          e = e > 0.f ? e : 0.2f * e;      // GATv2 leaky slope
          sc += e * (L ? atB[h*8+d0] : atA[h*8+d0]);
        }
        float p = __expf(sc);              // deferred-norm softmax
        z[L*2 + h] += p;
        #pragma unroll
        for (int d0 = 0; d0 < 8; ++d0) {
          int ix = L*16 + h*8 + d0;
          acc[ix] += p * fs[ix];
        }
      }
    }
  }
  // quad butterfly (quads are 4-lane aligned; whole quad alive or dead together)
  #pragma unroll
  for (int k = 0; k < 32; ++k) {
    acc[k] += __shfl_xor(acc[k], 1);
    acc[k] += __shfl_xor(acc[k], 2);
  }
  #pragma unroll
  for (int k = 0; k < 4; ++k) {
    z[k] += __shfl_xor(z[k], 1);
    z[k] += __shfl_xor(z[k], 2);
  }
  if (!alive) return;

  float xi[8]; load8(x + (size_t)n * 8, xi);
  uint32_t* row = hinb32 + (size_t)n * 32;   // 64 bf16 cols = 32 u32 words

  // layer 2 output (all lanes: needed for fused proj3)
  float v2[16];
  #pragma unroll
  for (int j = 0; j < 16; ++j) {
    float r = 0.f;
    #pragma unroll
    for (int i = 0; i < 8; ++i) r += xi[i] * r2[i*16 + j];
    float zz = z[2 + (j >> 3)];
    float v = (zz > 0.f ? acc[16 + j] / zz : 0.f) + r + b2s[j];
    v2[j] = elu1(v);
  }

  // layer 1: lane q computes cols 4q..4q+3 -> hinb words 2q,2q+1
  float v1[4];
  #pragma unroll
  for (int j = 0; j < 4; ++j) {
    int c = 4*q + j;
    float r = 0.f;
    #pragma unroll
    for (int i = 0; i < 8; ++i) r += xi[i] * r1[i*16 + c];
    float zz = z[c >> 3];
    float v = (zz > 0.f ? acc[c] / zz : 0.f) + r + b1s[c];
    v1[j] = elu1(v);
  }
  row[2*q]     = pack2(v1[0], v1[1]);
  row[2*q + 1] = pack2(v1[2], v1[3]);
  row[16 + q]  = pack2(xi[2*q], xi[2*q+1]);   // x -> cols 32..39
  row[20 + 3*q]     = 0u;                     // zeros -> cols 40..63
  row[20 + 3*q + 1] = 0u;
  row[20 + 3*q + 2] = 0u;

  // hdef1: lane q stores cols 4q..4q+3
  *(float4*)(hdef1 + (size_t)n * 16 + 4*q) =
      make_float4(v2[4*q], v2[4*q+1], v2[4*q+2], v2[4*q+3]);

  // fused proj3: lane q computes cols 4q..4q+3 of fs3 (bf16) / fd3 (fp32)
  float o1[4], o2[4];
  #pragma unroll
  for (int j = 0; j < 4; ++j) {
    int c = 4*q + j;
    float a1 = 0.f, a2 = 0.f;
    #pragma unroll
    for (int i = 0; i < 16; ++i) {
      a1 += v2[i] * ws3[i*16 + c];
      a2 += v2[i] * wd3[i*16 + c];
    }
    o1[j] = a1; o2[j] = a2;
  }
  fs3b[(size_t)n * 8 + 2*q]     = pack2(o1[0], o1[1]);
  fs3b[(size_t)n * 8 + 2*q + 1] = pack2(o1[2], o1[3]);
  *(float4*)(fd3 + (size_t)n * 16 + 4*q) = make_float4(o2[0], o2[1], o2[2], o2[3]);
}

__global__ __launch_bounds__(256) void gather3_k(
    const int* __restrict__ deg, const uint16_t* __restrict__ sb,
    const uint32_t* __restrict__ fs3b, const float* __restrict__ fd3,
    const float* __restrict__ at3, const float* __restrict__ bi3,
    const float* __restrict__ hdef1, uint32_t* __restrict__ hinb32) {
  __shared__ float at[16], b3[16];
  int tid = threadIdx.x;
  if (tid < 16) { at[tid] = at3[tid]; b3[tid] = bi3[tid]; }
  __syncthreads();
  int n = blockIdx.x * 64 + (tid >> 2);
  int q = tid & 3;
  bool alive = (n < NN);
  float fd[16];
  float acc[16];
  #pragma unroll
  for (int i = 0; i < 16; ++i) acc[i] = 0.f;
  float z[2] = {0.f, 0.f};
  int d = 0;
  const uint16_t* sp = sb + (size_t)n * CAP;
  if (alive) {
    load16(fd3 + (size_t)n * 16, fd);
    d = deg[n]; if (d > CAP) d = CAP;
  }
  for (int i = q; i < d; i += 4) {
    int s = sp[i];
    const uint4* fp = (const uint4*)(fs3b + (size_t)s * 8);
    uint4 u0 = fp[0], u1 = fp[1];
    uint32_t wv[8] = {u0.x,u0.y,u0.z,u0.w, u1.x,u1.y,u1.z,u1.w};
    float fs[16];
    #pragma unroll
    for (int k = 0; k < 8; ++k) unpack2(wv[k], fs[2*k], fs[2*k+1]);
    #pragma unroll
    for (int h = 0; h < 2; ++h) {
      float sc = 0.f;
      #pragma unroll
      for (int d0 = 0; d0 < 8; ++d0) {
        int ix = h*8 + d0;
        float e = fs[ix] + fd[ix];
        e = e > 0.f ? e : 0.2f * e;
        sc += e * at[ix];
      }
      float p = __expf(sc);
      z[h] += p;
      #pragma unroll
      for (int d0 = 0; d0 < 8; ++d0) {
        int ix = h*8 + d0;
        acc[ix] += p * fs[ix];
      }
    }
  }
  #pragma unroll
  for (int k = 0; k < 16; ++k) {
    acc[k] += __shfl_xor(acc[k], 1);
    acc[k] += __shfl_xor(acc[k], 2);
  }
  #pragma unroll
  for (int k = 0; k < 2; ++k) {
    z[k] += __shfl_xor(z[k], 1);
    z[k] += __shfl_xor(z[k], 2);
  }
  if (!alive) return;

  const float4 hv = *(const float4*)(hdef1 + (size_t)n * 16 + 4*q);
  float hd[4] = {hv.x, hv.y, hv.z, hv.w};
  uint32_t* row = hinb32 + (size_t)n * 32;
  float v[4];
  float zz = z[q >> 1];
  #pragma unroll
  for (int j = 0; j < 4; ++j) {
    int c = 4*q + j;
    float o = (zz > 0.f ? acc[c] / zz : 0.f) + hd[j] + b3[c];
    v[j] = elu1(o);
  }
  row[8 + 2*q]     = pack2(v[0], v[1]);
  row[8 + 2*q + 1] = pack2(v[2], v[3]);
}

// ---------------- MLP part (bf16 MFMA) ----------------

__device__ __forceinline__ void gload16(const void* g, void* l) {
  __builtin_amdgcn_global_load_lds((const __attribute__((address_space(1))) unsigned int*)g,
                                   (__attribute__((address_space(3))) unsigned int*)l, 16, 0, 0);
}

// BK=64, 128x128 tile, 4 waves 2x2, 64x64 per wave. Single-buffer 2-barrier
// structure (R3/R5-R9-proven). LDS tiles [128][64] bf16, XOR-swizzled.
template <bool OUT_BF16>
__device__ __forceinline__ void gemm_core(const uint16_t* __restrict__ A,
                                          const uint16_t* __restrict__ Bt,
                                          const float* __restrict__ bias,
                                          void* __restrict__ Cout,
                                          int K, int ldC, int Nreal, float slope,
                                          int bn, int bm) {
  __shared__ __align__(16) uint16_t As[128 * 64];
  __shared__ __align__(16) uint16_t Bs[128 * 64];
  const int tid = threadIdx.x;
  const int lane = tid & 63;
  const int wave = tid >> 6;
  const int wm = (wave >> 1) * 64;
  const int wn = (wave & 1) * 64;
  const long nt = (long)bn * 128;
  const long mt = (long)bm * 128;

  const int r0 = tid >> 3;
  const int kc = tid & 7;
  const int skc = kc ^ (r0 & 7);
  const uint16_t* Ag0 = A  + (mt + r0) * (long)K + skc * 8;
  const uint16_t* Bg0 = Bt + (nt + r0) * (long)K + skc * 8;
  uint16_t* Al0 = As + tid * 8;
  uint16_t* Bl0 = Bs + tid * 8;
  const long gstep = (long)32 * K;

  const int lr = lane & 15, kg = lane >> 4;
  const int x7 = lr & 7;
  const int sw0 = (kg ^ x7) * 8;
  const int sw1 = ((4 + kg) ^ x7) * 8;

  f32x4 acc[4][4] = {};

  for (int kk = 0; kk < K; kk += 64) {
    #pragma unroll
    for (int s = 0; s < 4; ++s) gload16(Ag0 + gstep*s + kk, Al0 + 2048*s);
    #pragma unroll
    for (int s = 0; s < 4; ++s) gload16(Bg0 + gstep*s + kk, Bl0 + 2048*s);
    __syncthreads();
    s16x8 b0[4], b1[4];
    #pragma unroll
    for (int j = 0; j < 4; ++j) {
      int rb = (wn + j*16 + lr) * 64;
      b0[j] = *(const s16x8*)(Bs + rb + sw0);
      b1[j] = *(const s16x8*)(Bs + rb + sw1);
    }
    #pragma unroll
    for (int i = 0; i < 4; ++i) {
      int rb = (wm + i*16 + lr) * 64;
      s16x8 a0 = *(const s16x8*)(As + rb + sw0);
      s16x8 a1 = *(const s16x8*)(As + rb + sw1);
      #pragma unroll
      for (int j = 0; j < 4; ++j) {
        acc[i][j] = __builtin_amdgcn_mfma_f32_16x16x32_bf16(a0, b0[j], acc[i][j], 0, 0, 0);
        acc[i][j] = __builtin_amdgcn_mfma_f32_16x16x32_bf16(a1, b1[j], acc[i][j], 0, 0, 0);
      }
    }
    __syncthreads();
  }

  // C/D layout (verified m89/m91): col = lane&15, row = (lane>>4)*4 + t
  const int cr = (lane >> 4) * 4;
  const int cc = lane & 15;
  #pragma unroll
  for (int j = 0; j < 4; ++j) {
    const long col = nt + wn + j*16 + cc;
    if (col >= Nreal) continue;
    const float bv = bias[col];
    #pragma unroll
    for (int i = 0; i < 4; ++i) {
      #pragma unroll
      for (int t = 0; t < 4; ++t) {
        const long row = mt + wm + i*16 + cr + t;
        float v = acc[i][j][t] + bv;
        v = v > 0.f ? v : slope * v;
        if (OUT_BF16) ((uint16_t*)Cout)[row * (long)ldC + col] = f2bf(v);
        else          ((float*)Cout)[row * (long)ldC + col] = v;
      }
    }
  }
}

__global__ __launch_bounds__(256) void gemm_l1(const uint16_t* __restrict__ A,
                                               const uint16_t* __restrict__ Bt,
                                               const float* __restrict__ bias,
                                               void* __restrict__ Cout) {
  gemm_core<true>(A, Bt, bias, Cout, 64, 1600, 1600, 0.01f, blockIdx.x, blockIdx.y);
}

// 1-D grid, m204 bijective XCD-chunked swizzle; n fast within a chunk (A-panel L2
// reuse). bm0 = m-tile offset: launched in two M-halves this round so the rocprof
// top-5 cutoff drops to ~124us and reveals the largest hidden kernel.
__global__ __launch_bounds__(256) void gemm_l2(const uint16_t* __restrict__ A,
                                               const uint16_t* __restrict__ Bt,
                                               const float* __restrict__ bias,
                                               void* __restrict__ Cout, int bm0) {
  const int nwg = gridDim.x;
  const int q = nwg >> 3, r = nwg & 7;
  const int xcd = blockIdx.x & 7, j = blockIdx.x >> 3;
  const int L = (xcd < r ? xcd * (q + 1) : r * (q + 1) + (xcd - r) * q) + j;
  gemm_core<true>(A, Bt, bias, Cout, 1600, 1600, 1600, 0.01f, L % 13, bm0 + L / 13);
}

// layer-3 GEMM with fused final projection + sigmoid (R9-proven)
__global__ __launch_bounds__(256) void gemm_l3f(const uint16_t* __restrict__ A,
                                                const uint16_t* __restrict__ Bt,
                                                const float* __restrict__ bias,
                                                const float* __restrict__ W4,
                                                const float* __restrict__ b4,
                                                float* __restrict__ out,
                                                long m0, long rows_real) {
  __shared__ __align__(16) uint16_t As[128 * 64];
  __shared__ __align__(16) uint16_t Bs[128 * 64];
  __shared__ float h3s[128][40];
  __shared__ float w4s[40];
  const int tid = threadIdx.x;
  const int lane = tid & 63;
  const int wave = tid >> 6;
  const int wm = (wave >> 1) * 64;
  const int wn = (wave & 1) * 64;
  const int K = 1600;
  const long mt = (long)blockIdx.y * 128;

  const int r0 = tid >> 3;
  const int kc = tid & 7;
  const int skc = kc ^ (r0 & 7);
  const uint16_t* Ag0 = A  + (mt + r0) * (long)K + skc * 8;
  const uint16_t* Bg0 = Bt + (long)r0 * K + skc * 8;   // nt = 0
  uint16_t* Al0 = As + tid * 8;
  uint16_t* Bl0 = Bs + tid * 8;
  const long gstep = (long)32 * K;

  const int lr = lane & 15, kg = lane >> 4;
  const int x7 = lr & 7;
  const int sw0 = (kg ^ x7) * 8;
  const int sw1 = ((4 + kg) ^ x7) * 8;

  f32x4 acc[4][4] = {};

  for (int kk = 0; kk < K; kk += 64) {
    #pragma unroll
    for (int s = 0; s < 4; ++s) gload16(Ag0 + gstep*s + kk, Al0 + 2048*s);
    #pragma unroll
    for (int s = 0; s < 4; ++s) gload16(Bg0 + gstep*s + kk, Bl0 + 2048*s);
    __syncthreads();
    s16x8 b0[4], b1[4];
    #pragma unroll
    for (int j = 0; j < 4; ++j) {
      int rb = (wn + j*16 + lr) * 64;
      b0[j] = *(const s16x8*)(Bs + rb + sw0);
      b1[j] = *(const s16x8*)(Bs + rb + sw1);
    }
    #pragma unroll
    for (int i = 0; i < 4; ++i) {
      int rb = (wm + i*16 + lr) * 64;
      s16x8 a0 = *(const s16x8*)(As + rb + sw0);
      s16x8 a1 = *(const s16x8*)(As + rb + sw1);
      #pragma unroll
      for (int j = 0; j < 4; ++j) {
        acc[i][j] = __builtin_amdgcn_mfma_f32_16x16x32_bf16(a0, b0[j], acc[i][j], 0, 0, 0);
        acc[i][j] = __builtin_amdgcn_mfma_f32_16x16x32_bf16(a1, b1[j], acc[i][j], 0, 0, 0);
      }
    }
    __syncthreads();
  }

  const int cr = (lane >> 4) * 4;
  const int cc = lane & 15;
  #pragma unroll
  for (int j = 0; j < 3; ++j) {
    const int col = wn + j*16 + cc;
    if (col < 40) {
      const float bv = bias[col];
      #pragma unroll
      for (int i = 0; i < 4; ++i) {
        #pragma unroll
        for (int t = 0; t < 4; ++t) {
          float v = acc[i][j][t] + bv;
          v = v > 0.f ? v : 0.01f * v;
          h3s[wm + i*16 + cr + t][col] = v;
        }
      }
    }
  }
  if (tid < 40) w4s[tid] = W4[tid];
  __syncthreads();

  if (tid < 128) {
    long grow = mt + tid;
    if (grow < rows_real) {
      float a = b4[0];
      #pragma unroll
      for (int k = 0; k < 40; ++k) a += h3s[tid][k] * w4s[k];
      out[m0 + grow] = 1.f / (1.f + __expf(-a));
    }
  }
}

// ---------------- host ----------------

extern "C" void kernel_launch(void* const* d_in, const int* in_sizes, int n_in,
                              void* d_out, int out_size, void* d_ws, size_t ws_size,
                              hipStream_t stream) {
  const float* x   = (const float*)d_in[0];
  const int*   src = (const int*)d_in[1];
  const int*   dst = (const int*)d_in[2];
  const float* Ws1 = (const float*)d_in[3];
  const float* Wd1 = (const float*)d_in[4];
  const float* at1 = (const float*)d_in[5];
  const float* bi1 = (const float*)d_in[6];
  const float* re1 = (const float*)d_in[7];
  const float* Ws2 = (const float*)d_in[8];
  const float* Wd2 = (const float*)d_in[9];
  const float* at2 = (const float*)d_in[10];
  const float* bi2 = (const float*)d_in[11];
  const float* re2 = (const float*)d_in[12];
  const float* Ws3 = (const float*)d_in[13];
  const float* Wd3 = (const float*)d_in[14];
  const float* at3 = (const float*)d_in[15];
  const float* bi3 = (const float*)d_in[16];
  const float* W1  = (const float*)d_in[17];
  const float* b1  = (const float*)d_in[18];
  const float* W2  = (const float*)d_in[19];
  const float* b2  = (const float*)d_in[20];
  const float* W3  = (const float*)d_in[21];
  const float* b3  = (const float*)d_in[22];
  const float* W4  = (const float*)d_in[23];
  const float* b4  = (const float*)d_in[24];
  float* out = (float*)d_out;

  char* ws = (char*)d_ws;
  size_t off = 0;
  auto alloc = [&](size_t bytes) -> void* {
    off = (off + 255) & ~(size_t)255;
    void* p = ws + off;
    off += bytes;
    return p;
  };
  // edge buckets
  int* deg      = (int*)alloc((size_t)NN * 4);
  uint16_t* sb  = (uint16_t*)alloc((size_t)NN * CAP * 2);
  // GAT features
  uint32_t* fs12b = (uint32_t*)alloc((size_t)NN * 16 * 4);  // 32 bf16/node (3.84MB: fits XCD L2)
  float* fd12     = (float*)alloc((size_t)NN * 32 * 4);
  uint32_t* fs3b  = (uint32_t*)alloc((size_t)NN * 8 * 4);   // 16 bf16/node (1.9MB)
  float* fd3      = (float*)alloc((size_t)NN * 16 * 4);
  float* hdef1    = (float*)alloc((size_t)NN * 16 * 4);
  // MLP
  uint16_t* hinb = (uint16_t*)alloc((size_t)60032 * 64 * 2);
  uint16_t* W1T  = (uint16_t*)alloc((size_t)1664 * 64 * 2);
  uint16_t* W2T  = (uint16_t*)alloc((size_t)1664 * 1600 * 2);
  uint16_t* W3T  = (uint16_t*)alloc((size_t)128 * 1600 * 2);

  size_t fixed_end = (off + 255) & ~(size_t)255;
  size_t avail = (ws_size > fixed_end + 4096) ? (ws_size - fixed_end - 4096) : 0;
  long mc = (long)(avail / 6400);        // per-row bytes: 2 x 1600 x 2B (h1c + h2c)
  mc = (mc / 128) * 128;
  if (mc > 60032) mc = 60032;
  if (mc < 128) mc = 128;
  uint16_t* h1c = (uint16_t*)alloc((size_t)mc * 1600 * 2);
  uint16_t* h2c = (uint16_t*)alloc((size_t)mc * 1600 * 2);

  hipMemsetAsync(deg, 0, (size_t)NN * 4, stream);

  // fused prep: bucket (8 passes) | weight transposes | proj12
  prep_k<<<8 * EB4 + 2700 + NB_NODE, 256, 0, stream>>>(
      src, dst, deg, sb, W1, W2, W3, W1T, W2T, W3T,
      x, Ws1, Wd1, Ws2, Wd2, fs12b, fd12);

  // GAT gathers
  gather12_p3<<<NB_QUAD, 256, 0, stream>>>(deg, sb, fs12b, fd12, at1, at2,
                                           x, re1, bi1, re2, bi2, Ws3, Wd3,
                                           (uint32_t*)hinb, hdef1, fs3b, fd3);
  gather3_k<<<NB_QUAD, 256, 0, stream>>>(deg, sb, fs3b, fd3, at3, bi3,
                                         hdef1, (uint32_t*)hinb);

  // MLP
  for (long m0 = 0; m0 < NN; m0 += mc) {
    long rows_real = NN - m0; if (rows_real > mc) rows_real = mc;
    long rows_pad = (rows_real + 127) & ~127L;
    unsigned mtiles = (unsigned)(rows_pad / 128);
    gemm_l1<<<dim3(13, mtiles), 256, 0, stream>>>(hinb + m0 * 64, W1T, b1, h1c);
    // visibility split: two M-halves (each ~124us) lower the top-5 cutoff so the
    // largest hidden kernel shows by name next profile. Known cost ~25us (R6).
    unsigned mtA = mtiles / 2, mtB = mtiles - mtA;
    if (mtA) gemm_l2<<<13 * mtA, 256, 0, stream>>>(h1c, W2T, b2, h2c, 0);
    if (mtB) gemm_l2<<<13 * mtB, 256, 0, stream>>>(h1c, W2T, b2, h2c, (int)mtA);
    gemm_l3f<<<dim3(1, mtiles), 256, 0, stream>>>(h2c, W3T, b3, W4, b4, out, m0, rows_real);
  }
}

// Round 11
// 724.162 us; speedup vs baseline: 1.0951x; 1.0951x over previous
//
#include <hip/hip_runtime.h>
#include <stdint.h>

#define NN 60000
#define NE 1920000
#define NB_NODE 235   // ceil(60000/256)
#define NB_QUAD 938   // ceil(60000/64) for 4-thread-per-node kernels
#define EB4 1875      // NE/(256*4) exactly: blocks per bucket pass
#define CAP 128       // bucket capacity per node (P(deg>=128) ~ 0, dataset fixed)
#define RN 7500       // dst-range width per pass (60000/8): 7500*128*2B = 1.9MB < 4MB L2

typedef float f32x4 __attribute__((ext_vector_type(4)));
typedef short s16x8 __attribute__((ext_vector_type(8)));

__device__ __forceinline__ uint16_t f2bf(float f) {
  union { float f; uint32_t u; } v; v.f = f;
  uint32_t r = v.u + 0x7FFFu + ((v.u >> 16) & 1u);
  return (uint16_t)(r >> 16);
}
__device__ __forceinline__ uint32_t pack2(float a, float b) {
  return (uint32_t)f2bf(a) | ((uint32_t)f2bf(b) << 16);
}
__device__ __forceinline__ void unpack2(uint32_t w, float& lo, float& hi) {
  union { uint32_t u; float f; } a, b;
  a.u = w << 16; b.u = w & 0xffff0000u;
  lo = a.f; hi = b.f;
}
__device__ __forceinline__ float elu1(float x) { return x > 0.f ? x : (__expf(x) - 1.f); }

__device__ __forceinline__ void load8(const float* __restrict__ p, float* v) {
  const float4* q = (const float4*)p;
  float4 a = q[0], b = q[1];
  v[0]=a.x; v[1]=a.y; v[2]=a.z; v[3]=a.w; v[4]=b.x; v[5]=b.y; v[6]=b.z; v[7]=b.w;
}
__device__ __forceinline__ void load16(const float* __restrict__ p, float* v) {
  load8(p, v); load8(p + 8, v + 8);
}
__device__ __forceinline__ void store16(float* __restrict__ p, const float* v) {
  float4* q = (float4*)p;
  q[0] = make_float4(v[0],v[1],v[2],v[3]);
  q[1] = make_float4(v[4],v[5],v[6],v[7]);
  q[2] = make_float4(v[8],v[9],v[10],v[11]);
  q[3] = make_float4(v[12],v[13],v[14],v[15]);
}

// ---------------- fused prep: bucket (15000 blk) | transposes (2700) | proj12 (235) ----
__global__ void prep_k(const int* __restrict__ src, const int* __restrict__ dst,
                       int* __restrict__ deg, uint16_t* __restrict__ sb,
                       const float* __restrict__ W1, const float* __restrict__ W2,
                       const float* __restrict__ W3,
                       uint16_t* __restrict__ W1T, uint16_t* __restrict__ W2T,
                       uint16_t* __restrict__ W3T,
                       const float* __restrict__ x,
                       const float* __restrict__ Ws1, const float* __restrict__ Wd1,
                       const float* __restrict__ Ws2, const float* __restrict__ Wd2,
                       uint32_t* __restrict__ fs12b, float* __restrict__ fd12) {
  int b = blockIdx.x;
  int tid = threadIdx.x;

  if (b < 8 * EB4) {
    // --- bucket: pass p handles dst in [p*RN,(p+1)*RN); 4 edges/thread via int4 ---
    int p = b / EB4;
    int idx = (b - p * EB4) * 256 + tid;
    int4 d4 = ((const int4*)dst)[idx];
    int4 s4 = ((const int4*)src)[idx];
    int lo = p * RN;
    int dd[4] = {d4.x, d4.y, d4.z, d4.w};
    int ss[4] = {s4.x, s4.y, s4.z, s4.w};
    #pragma unroll
    for (int j = 0; j < 4; ++j) {
      int d = dd[j];
      if (d >= lo && d < lo + RN) {
        int pos = atomicAdd(&deg[d], 1);
        if (pos < CAP) sb[(size_t)d * CAP + pos] = (uint16_t)ss[j];
      }
    }
    return;
  }
  b -= 8 * EB4;

  if (b < 2700) {
    // --- weight transposes to bf16 ---
    __shared__ float t[32][33];
    const float* in; uint16_t* outT; int R, C, ldout, rb, cb;
    if (b < 100)       { in = W1; outT = W1T; R = 40;   C = 1600; ldout = 64;
                         rb = (b % 2) * 32;        cb = (b / 2) * 32; }
    else if (b < 2600) { int u = b - 100; in = W2; outT = W2T; R = 1600; C = 1600; ldout = 1600;
                         rb = (u % 50) * 32;       cb = (u / 50) * 32; }
    else               { int u = b - 2600; in = W3; outT = W3T; R = 1600; C = 40;  ldout = 1600;
                         rb = (u % 50) * 32;       cb = (u / 50) * 32; }
    int tx = tid & 31, ty = tid >> 5;
    #pragma unroll
    for (int y = ty; y < 32; y += 8) {
      int r = rb + y, c = cb + tx;
      t[y][tx] = (r < R && c < C) ? in[(size_t)r * C + c] : 0.f;
    }
    __syncthreads();
    #pragma unroll
    for (int y = ty; y < 32; y += 8) {
      int c = cb + y, r = rb + tx;
      if (c < C && r < R) outT[(size_t)c * ldout + r] = f2bf(t[tx][y]);
    }
    return;
  }
  b -= 2700;

  // --- proj12: fs12b bf16 [fs1|fs2], fd12 fp32 [fd1|fd2] ---
  __shared__ float w[4][128];
  if (tid < 128) {
    w[0][tid] = Ws1[tid]; w[1][tid] = Wd1[tid];
    w[2][tid] = Ws2[tid]; w[3][tid] = Wd2[tid];
  }
  __syncthreads();
  int n = b * 256 + tid;
  if (n >= NN) return;
  float xi[8]; load8(x + (size_t)n * 8, xi);
  float o[16];
  uint32_t fsw[16];
  #pragma unroll
  for (int m = 0; m < 4; ++m) {
    #pragma unroll
    for (int j = 0; j < 16; ++j) {
      float a = 0.f;
      #pragma unroll
      for (int i = 0; i < 8; ++i) a += xi[i] * w[m][i*16 + j];
      o[j] = a;
    }
    if (m & 1) {
      store16(fd12 + (size_t)n * 32 + (m >> 1) * 16, o);
    } else {
      #pragma unroll
      for (int j = 0; j < 8; ++j) fsw[(m >> 1) * 8 + j] = pack2(o[2*j], o[2*j+1]);
    }
  }
  uint4* fp = (uint4*)(fs12b + (size_t)n * 16);
  fp[0] = make_uint4(fsw[0], fsw[1], fsw[2], fsw[3]);
  fp[1] = make_uint4(fsw[4], fsw[5], fsw[6], fsw[7]);
  fp[2] = make_uint4(fsw[8], fsw[9], fsw[10], fsw[11]);
  fp[3] = make_uint4(fsw[12], fsw[13], fsw[14], fsw[15]);
}

// ---------------- gathers (4 threads per node, quad-shfl-combined; R7/R10-proven) ---
// Note: lane-count sweeps (2/4/8, R5/R8/R10) were all ~neutral -> gathers are bound
// by the inherent 1.92M random 64B reads, not chain depth or TLP. Left untouched.

__global__ __launch_bounds__(256) void gather12_p3(
    const int* __restrict__ deg, const uint16_t* __restrict__ sb,
    const uint32_t* __restrict__ fs12b, const float* __restrict__ fd12,
    const float* __restrict__ at1, const float* __restrict__ at2,
    const float* __restrict__ x,
    const float* __restrict__ re1, const float* __restrict__ bi1,
    const float* __restrict__ re2, const float* __restrict__ bi2,
    const float* __restrict__ Ws3, const float* __restrict__ Wd3,
    uint32_t* __restrict__ hinb32, float* __restrict__ hdef1,
    uint32_t* __restrict__ fs3b, float* __restrict__ fd3) {
  __shared__ float r1[128], r2[128], ws3[256], wd3[256];
  __shared__ float atA[16], atB[16], b1s[16], b2s[16];
  int tid = threadIdx.x;
  if (tid < 128) { r1[tid] = re1[tid]; r2[tid] = re2[tid]; }
  ws3[tid] = Ws3[tid]; wd3[tid] = Wd3[tid];
  if (tid < 16) { atA[tid] = at1[tid]; atB[tid] = at2[tid];
                  b1s[tid] = bi1[tid]; b2s[tid] = bi2[tid]; }
  __syncthreads();
  int n = blockIdx.x * 64 + (tid >> 2);
  int q = tid & 3;
  bool alive = (n < NN);
  float fd[32];
  float acc[32];
  #pragma unroll
  for (int i = 0; i < 32; ++i) acc[i] = 0.f;
  float z[4] = {0.f, 0.f, 0.f, 0.f};
  int d = 0;
  const uint16_t* sp = sb + (size_t)n * CAP;
  if (alive) {
    load16(fd12 + (size_t)n * 32, fd);
    load16(fd12 + (size_t)n * 32 + 16, fd + 16);
    d = deg[n]; if (d > CAP) d = CAP;
  }
  for (int i = q; i < d; i += 4) {
    int s = sp[i];
    const uint4* fp = (const uint4*)(fs12b + (size_t)s * 16);
    uint4 u0 = fp[0], u1 = fp[1], u2 = fp[2], u3 = fp[3];
    uint32_t wv[16] = {u0.x,u0.y,u0.z,u0.w, u1.x,u1.y,u1.z,u1.w,
                       u2.x,u2.y,u2.z,u2.w, u3.x,u3.y,u3.z,u3.w};
    float fs[32];
    #pragma unroll
    for (int k = 0; k < 16; ++k) unpack2(wv[k], fs[2*k], fs[2*k+1]);
    #pragma unroll
    for (int L = 0; L < 2; ++L) {
      #pragma unroll
      for (int h = 0; h < 2; ++h) {
        float sc = 0.f;
        #pragma unroll
        for (int d0 = 0; d0 < 8; ++d0) {
          int ix = L*16 + h*8 + d0;
          float e = fs[ix] + fd[ix];
          e = e > 0.f ? e : 0.2f * e;      // GATv2 leaky slope
          sc += e * (L ? atB[h*8+d0] : atA[h*8+d0]);
        }
        float p = __expf(sc);              // deferred-norm softmax
        z[L*2 + h] += p;
        #pragma unroll
        for (int d0 = 0; d0 < 8; ++d0) {
          int ix = L*16 + h*8 + d0;
          acc[ix] += p * fs[ix];
        }
      }
    }
  }
  // quad butterfly (quads are 4-lane aligned; whole quad alive or dead together)
  #pragma unroll
  for (int k = 0; k < 32; ++k) {
    acc[k] += __shfl_xor(acc[k], 1);
    acc[k] += __shfl_xor(acc[k], 2);
  }
  #pragma unroll
  for (int k = 0; k < 4; ++k) {
    z[k] += __shfl_xor(z[k], 1);
    z[k] += __shfl_xor(z[k], 2);
  }
  if (!alive) return;

  float xi[8]; load8(x + (size_t)n * 8, xi);
  uint32_t* row = hinb32 + (size_t)n * 32;   // 64 bf16 cols = 32 u32 words

  // layer 2 output (all lanes: needed for fused proj3)
  float v2[16];
  #pragma unroll
  for (int j = 0; j < 16; ++j) {
    float r = 0.f;
    #pragma unroll
    for (int i = 0; i < 8; ++i) r += xi[i] * r2[i*16 + j];
    float zz = z[2 + (j >> 3)];
    float v = (zz > 0.f ? acc[16 + j] / zz : 0.f) + r + b2s[j];
    v2[j] = elu1(v);
  }

  // layer 1: lane q computes cols 4q..4q+3 -> hinb words 2q,2q+1
  float v1[4];
  #pragma unroll
  for (int j = 0; j < 4; ++j) {
    int c = 4*q + j;
    float r = 0.f;
    #pragma unroll
    for (int i = 0; i < 8; ++i) r += xi[i] * r1[i*16 + c];
    float zz = z[c >> 3];
    float v = (zz > 0.f ? acc[c] / zz : 0.f) + r + b1s[c];
    v1[j] = elu1(v);
  }
  row[2*q]     = pack2(v1[0], v1[1]);
  row[2*q + 1] = pack2(v1[2], v1[3]);
  row[16 + q]  = pack2(xi[2*q], xi[2*q+1]);   // x -> cols 32..39
  row[20 + 3*q]     = 0u;                     // zeros -> cols 40..63
  row[20 + 3*q + 1] = 0u;
  row[20 + 3*q + 2] = 0u;

  // hdef1: lane q stores cols 4q..4q+3
  *(float4*)(hdef1 + (size_t)n * 16 + 4*q) =
      make_float4(v2[4*q], v2[4*q+1], v2[4*q+2], v2[4*q+3]);

  // fused proj3: lane q computes cols 4q..4q+3 of fs3 (bf16) / fd3 (fp32)
  float o1[4], o2[4];
  #pragma unroll
  for (int j = 0; j < 4; ++j) {
    int c = 4*q + j;
    float a1 = 0.f, a2 = 0.f;
    #pragma unroll
    for (int i = 0; i < 16; ++i) {
      a1 += v2[i] * ws3[i*16 + c];
      a2 += v2[i] * wd3[i*16 + c];
    }
    o1[j] = a1; o2[j] = a2;
  }
  fs3b[(size_t)n * 8 + 2*q]     = pack2(o1[0], o1[1]);
  fs3b[(size_t)n * 8 + 2*q + 1] = pack2(o1[2], o1[3]);
  *(float4*)(fd3 + (size_t)n * 16 + 4*q) = make_float4(o2[0], o2[1], o2[2], o2[3]);
}

__global__ __launch_bounds__(256) void gather3_k(
    const int* __restrict__ deg, const uint16_t* __restrict__ sb,
    const uint32_t* __restrict__ fs3b, const float* __restrict__ fd3,
    const float* __restrict__ at3, const float* __restrict__ bi3,
    const float* __restrict__ hdef1, uint32_t* __restrict__ hinb32) {
  __shared__ float at[16], b3[16];
  int tid = threadIdx.x;
  if (tid < 16) { at[tid] = at3[tid]; b3[tid] = bi3[tid]; }
  __syncthreads();
  int n = blockIdx.x * 64 + (tid >> 2);
  int q = tid & 3;
  bool alive = (n < NN);
  float fd[16];
  float acc[16];
  #pragma unroll
  for (int i = 0; i < 16; ++i) acc[i] = 0.f;
  float z[2] = {0.f, 0.f};
  int d = 0;
  const uint16_t* sp = sb + (size_t)n * CAP;
  if (alive) {
    load16(fd3 + (size_t)n * 16, fd);
    d = deg[n]; if (d > CAP) d = CAP;
  }
  for (int i = q; i < d; i += 4) {
    int s = sp[i];
    const uint4* fp = (const uint4*)(fs3b + (size_t)s * 8);
    uint4 u0 = fp[0], u1 = fp[1];
    uint32_t wv[8] = {u0.x,u0.y,u0.z,u0.w, u1.x,u1.y,u1.z,u1.w};
    float fs[16];
    #pragma unroll
    for (int k = 0; k < 8; ++k) unpack2(wv[k], fs[2*k], fs[2*k+1]);
    #pragma unroll
    for (int h = 0; h < 2; ++h) {
      float sc = 0.f;
      #pragma unroll
      for (int d0 = 0; d0 < 8; ++d0) {
        int ix = h*8 + d0;
        float e = fs[ix] + fd[ix];
        e = e > 0.f ? e : 0.2f * e;
        sc += e * at[ix];
      }
      float p = __expf(sc);
      z[h] += p;
      #pragma unroll
      for (int d0 = 0; d0 < 8; ++d0) {
        int ix = h*8 + d0;
        acc[ix] += p * fs[ix];
      }
    }
  }
  #pragma unroll
  for (int k = 0; k < 16; ++k) {
    acc[k] += __shfl_xor(acc[k], 1);
    acc[k] += __shfl_xor(acc[k], 2);
  }
  #pragma unroll
  for (int k = 0; k < 2; ++k) {
    z[k] += __shfl_xor(z[k], 1);
    z[k] += __shfl_xor(z[k], 2);
  }
  if (!alive) return;

  const float4 hv = *(const float4*)(hdef1 + (size_t)n * 16 + 4*q);
  float hd[4] = {hv.x, hv.y, hv.z, hv.w};
  uint32_t* row = hinb32 + (size_t)n * 32;
  float v[4];
  float zz = z[q >> 1];
  #pragma unroll
  for (int j = 0; j < 4; ++j) {
    int c = 4*q + j;
    float o = (zz > 0.f ? acc[c] / zz : 0.f) + hd[j] + b3[c];
    v[j] = elu1(o);
  }
  row[8 + 2*q]     = pack2(v[0], v[1]);
  row[8 + 2*q + 1] = pack2(v[2], v[3]);
}

// ---------------- MLP part (bf16 MFMA) ----------------

__device__ __forceinline__ void gload16(const void* g, void* l) {
  __builtin_amdgcn_global_load_lds((const __attribute__((address_space(1))) unsigned int*)g,
                                   (__attribute__((address_space(3))) unsigned int*)l, 16, 0, 0);
}

// BK=64, 128x128 tile, 4 waves 2x2, 64x64 per wave. Single-buffer 2-barrier
// structure (R3/R5-R10-proven). LDS tiles [128][64] bf16, XOR-swizzled.
template <bool OUT_BF16>
__device__ __forceinline__ void gemm_core(const uint16_t* __restrict__ A,
                                          const uint16_t* __restrict__ Bt,
                                          const float* __restrict__ bias,
                                          void* __restrict__ Cout,
                                          int K, int ldC, int Nreal, float slope,
                                          int bn, int bm) {
  __shared__ __align__(16) uint16_t As[128 * 64];
  __shared__ __align__(16) uint16_t Bs[128 * 64];
  const int tid = threadIdx.x;
  const int lane = tid & 63;
  const int wave = tid >> 6;
  const int wm = (wave >> 1) * 64;
  const int wn = (wave & 1) * 64;
  const long nt = (long)bn * 128;
  const long mt = (long)bm * 128;

  const int r0 = tid >> 3;
  const int kc = tid & 7;
  const int skc = kc ^ (r0 & 7);
  const uint16_t* Ag0 = A  + (mt + r0) * (long)K + skc * 8;
  const uint16_t* Bg0 = Bt + (nt + r0) * (long)K + skc * 8;
  uint16_t* Al0 = As + tid * 8;
  uint16_t* Bl0 = Bs + tid * 8;
  const long gstep = (long)32 * K;

  const int lr = lane & 15, kg = lane >> 4;
  const int x7 = lr & 7;
  const int sw0 = (kg ^ x7) * 8;
  const int sw1 = ((4 + kg) ^ x7) * 8;

  f32x4 acc[4][4] = {};

  for (int kk = 0; kk < K; kk += 64) {
    #pragma unroll
    for (int s = 0; s < 4; ++s) gload16(Ag0 + gstep*s + kk, Al0 + 2048*s);
    #pragma unroll
    for (int s = 0; s < 4; ++s) gload16(Bg0 + gstep*s + kk, Bl0 + 2048*s);
    __syncthreads();
    s16x8 b0[4], b1[4];
    #pragma unroll
    for (int j = 0; j < 4; ++j) {
      int rb = (wn + j*16 + lr) * 64;
      b0[j] = *(const s16x8*)(Bs + rb + sw0);
      b1[j] = *(const s16x8*)(Bs + rb + sw1);
    }
    #pragma unroll
    for (int i = 0; i < 4; ++i) {
      int rb = (wm + i*16 + lr) * 64;
      s16x8 a0 = *(const s16x8*)(As + rb + sw0);
      s16x8 a1 = *(const s16x8*)(As + rb + sw1);
      #pragma unroll
      for (int j = 0; j < 4; ++j) {
        acc[i][j] = __builtin_amdgcn_mfma_f32_16x16x32_bf16(a0, b0[j], acc[i][j], 0, 0, 0);
        acc[i][j] = __builtin_amdgcn_mfma_f32_16x16x32_bf16(a1, b1[j], acc[i][j], 0, 0, 0);
      }
    }
    __syncthreads();
  }

  // C/D layout (verified m89/m91): col = lane&15, row = (lane>>4)*4 + t
  const int cr = (lane >> 4) * 4;
  const int cc = lane & 15;
  #pragma unroll
  for (int j = 0; j < 4; ++j) {
    const long col = nt + wn + j*16 + cc;
    if (col >= Nreal) continue;
    const float bv = bias[col];
    #pragma unroll
    for (int i = 0; i < 4; ++i) {
      #pragma unroll
      for (int t = 0; t < 4; ++t) {
        const long row = mt + wm + i*16 + cr + t;
        float v = acc[i][j][t] + bv;
        v = v > 0.f ? v : slope * v;
        if (OUT_BF16) ((uint16_t*)Cout)[row * (long)ldC + col] = f2bf(v);
        else          ((float*)Cout)[row * (long)ldC + col] = v;
      }
    }
  }
}

__global__ __launch_bounds__(256) void gemm_l1(const uint16_t* __restrict__ A,
                                               const uint16_t* __restrict__ Bt,
                                               const float* __restrict__ bias,
                                               void* __restrict__ Cout) {
  gemm_core<true>(A, Bt, bias, Cout, 64, 1600, 1600, 0.01f, blockIdx.x, blockIdx.y);
}

// 1-D grid, m204 bijective XCD-chunked swizzle; n fast within a chunk (A-panel L2
// reuse). One launch per M-chunk (~235 mtiles): each dispatch ~124us so top-5
// visibility is preserved without a split tax.
__global__ __launch_bounds__(256) void gemm_l2(const uint16_t* __restrict__ A,
                                               const uint16_t* __restrict__ Bt,
                                               const float* __restrict__ bias,
                                               void* __restrict__ Cout) {
  const int nwg = gridDim.x;
  const int q = nwg >> 3, r = nwg & 7;
  const int xcd = blockIdx.x & 7, j = blockIdx.x >> 3;
  const int L = (xcd < r ? xcd * (q + 1) : r * (q + 1) + (xcd - r) * q) + j;
  gemm_core<true>(A, Bt, bias, Cout, 1600, 1600, 1600, 0.01f, L % 13, L / 13);
}

// layer-3 GEMM with fused final projection + sigmoid (R9/R10-proven)
__global__ __launch_bounds__(256) void gemm_l3f(const uint16_t* __restrict__ A,
                                                const uint16_t* __restrict__ Bt,
                                                const float* __restrict__ bias,
                                                const float* __restrict__ W4,
                                                const float* __restrict__ b4,
                                                float* __restrict__ out,
                                                long m0, long rows_real) {
  __shared__ __align__(16) uint16_t As[128 * 64];
  __shared__ __align__(16) uint16_t Bs[128 * 64];
  __shared__ float h3s[128][40];
  __shared__ float w4s[40];
  const int tid = threadIdx.x;
  const int lane = tid & 63;
  const int wave = tid >> 6;
  const int wm = (wave >> 1) * 64;
  const int wn = (wave & 1) * 64;
  const int K = 1600;
  const long mt = (long)blockIdx.y * 128;

  const int r0 = tid >> 3;
  const int kc = tid & 7;
  const int skc = kc ^ (r0 & 7);
  const uint16_t* Ag0 = A  + (mt + r0) * (long)K + skc * 8;
  const uint16_t* Bg0 = Bt + (long)r0 * K + skc * 8;   // nt = 0
  uint16_t* Al0 = As + tid * 8;
  uint16_t* Bl0 = Bs + tid * 8;
  const long gstep = (long)32 * K;

  const int lr = lane & 15, kg = lane >> 4;
  const int x7 = lr & 7;
  const int sw0 = (kg ^ x7) * 8;
  const int sw1 = ((4 + kg) ^ x7) * 8;

  f32x4 acc[4][4] = {};

  for (int kk = 0; kk < K; kk += 64) {
    #pragma unroll
    for (int s = 0; s < 4; ++s) gload16(Ag0 + gstep*s + kk, Al0 + 2048*s);
    #pragma unroll
    for (int s = 0; s < 4; ++s) gload16(Bg0 + gstep*s + kk, Bl0 + 2048*s);
    __syncthreads();
    s16x8 b0[4], b1[4];
    #pragma unroll
    for (int j = 0; j < 4; ++j) {
      int rb = (wn + j*16 + lr) * 64;
      b0[j] = *(const s16x8*)(Bs + rb + sw0);
      b1[j] = *(const s16x8*)(Bs + rb + sw1);
    }
    #pragma unroll
    for (int i = 0; i < 4; ++i) {
      int rb = (wm + i*16 + lr) * 64;
      s16x8 a0 = *(const s16x8*)(As + rb + sw0);
      s16x8 a1 = *(const s16x8*)(As + rb + sw1);
      #pragma unroll
      for (int j = 0; j < 4; ++j) {
        acc[i][j] = __builtin_amdgcn_mfma_f32_16x16x32_bf16(a0, b0[j], acc[i][j], 0, 0, 0);
        acc[i][j] = __builtin_amdgcn_mfma_f32_16x16x32_bf16(a1, b1[j], acc[i][j], 0, 0, 0);
      }
    }
    __syncthreads();
  }

  const int cr = (lane >> 4) * 4;
  const int cc = lane & 15;
  #pragma unroll
  for (int j = 0; j < 3; ++j) {
    const int col = wn + j*16 + cc;
    if (col < 40) {
      const float bv = bias[col];
      #pragma unroll
      for (int i = 0; i < 4; ++i) {
        #pragma unroll
        for (int t = 0; t < 4; ++t) {
          float v = acc[i][j][t] + bv;
          v = v > 0.f ? v : 0.01f * v;
          h3s[wm + i*16 + cr + t][col] = v;
        }
      }
    }
  }
  if (tid < 40) w4s[tid] = W4[tid];
  __syncthreads();

  if (tid < 128) {
    long grow = mt + tid;
    if (grow < rows_real) {
      float a = b4[0];
      #pragma unroll
      for (int k = 0; k < 40; ++k) a += h3s[tid][k] * w4s[k];
      out[m0 + grow] = 1.f / (1.f + __expf(-a));
    }
  }
}

// ---------------- host ----------------

extern "C" void kernel_launch(void* const* d_in, const int* in_sizes, int n_in,
                              void* d_out, int out_size, void* d_ws, size_t ws_size,
                              hipStream_t stream) {
  const float* x   = (const float*)d_in[0];
  const int*   src = (const int*)d_in[1];
  const int*   dst = (const int*)d_in[2];
  const float* Ws1 = (const float*)d_in[3];
  const float* Wd1 = (const float*)d_in[4];
  const float* at1 = (const float*)d_in[5];
  const float* bi1 = (const float*)d_in[6];
  const float* re1 = (const float*)d_in[7];
  const float* Ws2 = (const float*)d_in[8];
  const float* Wd2 = (const float*)d_in[9];
  const float* at2 = (const float*)d_in[10];
  const float* bi2 = (const float*)d_in[11];
  const float* re2 = (const float*)d_in[12];
  const float* Ws3 = (const float*)d_in[13];
  const float* Wd3 = (const float*)d_in[14];
  const float* at3 = (const float*)d_in[15];
  const float* bi3 = (const float*)d_in[16];
  const float* W1  = (const float*)d_in[17];
  const float* b1  = (const float*)d_in[18];
  const float* W2  = (const float*)d_in[19];
  const float* b2  = (const float*)d_in[20];
  const float* W3  = (const float*)d_in[21];
  const float* b3  = (const float*)d_in[22];
  const float* W4  = (const float*)d_in[23];
  const float* b4  = (const float*)d_in[24];
  float* out = (float*)d_out;

  char* ws = (char*)d_ws;
  size_t off = 0;
  auto alloc = [&](size_t bytes) -> void* {
    off = (off + 255) & ~(size_t)255;
    void* p = ws + off;
    off += bytes;
    return p;
  };
  // edge buckets
  int* deg      = (int*)alloc((size_t)NN * 4);
  uint16_t* sb  = (uint16_t*)alloc((size_t)NN * CAP * 2);
  // GAT features
  uint32_t* fs12b = (uint32_t*)alloc((size_t)NN * 16 * 4);  // 32 bf16/node (3.84MB: fits XCD L2)
  float* fd12     = (float*)alloc((size_t)NN * 32 * 4);
  uint32_t* fs3b  = (uint32_t*)alloc((size_t)NN * 8 * 4);   // 16 bf16/node (1.9MB)
  float* fd3      = (float*)alloc((size_t)NN * 16 * 4);
  float* hdef1    = (float*)alloc((size_t)NN * 16 * 4);
  // MLP
  uint16_t* hinb = (uint16_t*)alloc((size_t)60032 * 64 * 2);
  uint16_t* W1T  = (uint16_t*)alloc((size_t)1664 * 64 * 2);
  uint16_t* W2T  = (uint16_t*)alloc((size_t)1664 * 1600 * 2);
  uint16_t* W3T  = (uint16_t*)alloc((size_t)128 * 1600 * 2);

  size_t fixed_end = (off + 255) & ~(size_t)255;
  size_t avail = (ws_size > fixed_end + 4096) ? (ws_size - fixed_end - 4096) : 0;
  long mc = (long)(avail / 6400);        // per-row bytes: 2 x 1600 x 2B (h1c + h2c)
  mc = (mc / 128) * 128;
  // Cap at ~half the node set: per-chunk h1c+h2c = 192MB <= 256MB L3, so gemm_l2's
  // A-reads and gemm_l3f's reads are L3-resident (R10 counters showed ~232MB HBM
  // FETCH at full-size chunks -> h1c was thrashed out of L3 before being re-read).
  if (mc > 30080) mc = 30080;
  if (mc < 128) mc = 128;
  uint16_t* h1c = (uint16_t*)alloc((size_t)mc * 1600 * 2);
  uint16_t* h2c = (uint16_t*)alloc((size_t)mc * 1600 * 2);

  hipMemsetAsync(deg, 0, (size_t)NN * 4, stream);

  // fused prep: bucket (8 passes) | weight transposes | proj12
  prep_k<<<8 * EB4 + 2700 + NB_NODE, 256, 0, stream>>>(
      src, dst, deg, sb, W1, W2, W3, W1T, W2T, W3T,
      x, Ws1, Wd1, Ws2, Wd2, fs12b, fd12);

  // GAT gathers
  gather12_p3<<<NB_QUAD, 256, 0, stream>>>(deg, sb, fs12b, fd12, at1, at2,
                                           x, re1, bi1, re2, bi2, Ws3, Wd3,
                                           (uint32_t*)hinb, hdef1, fs3b, fd3);
  gather3_k<<<NB_QUAD, 256, 0, stream>>>(deg, sb, fs3b, fd3, at3, bi3,
                                         hdef1, (uint32_t*)hinb);

  // MLP (2 chunks: h1c/h2c L3-resident per chunk)
  for (long m0 = 0; m0 < NN; m0 += mc) {
    long rows_real = NN - m0; if (rows_real > mc) rows_real = mc;
    long rows_pad = (rows_real + 127) & ~127L;
    unsigned mtiles = (unsigned)(rows_pad / 128);
    gemm_l1<<<dim3(13, mtiles), 256, 0, stream>>>(hinb + m0 * 64, W1T, b1, h1c);
    gemm_l2<<<13 * mtiles, 256, 0, stream>>>(h1c, W2T, b2, h2c);
    gemm_l3f<<<dim3(1, mtiles), 256, 0, stream>>>(h2c, W3T, b3, W4, b4, out, m0, rows_real);
  }
}